// Round 1
// baseline (623.806 us; speedup 1.0000x reference)
//
#include <hip/hip_runtime.h>
#include <stdint.h>

// Problem constants (fixed by the reference: B=2, S=2048, D=2048, H=16)
#define SQ_S 2048
#define DIM 2048
#define NH 16
#define HD 128
#define NB 2
#define NROWS (NB * SQ_S) // 4096

typedef __bf16 bf16x8 __attribute__((ext_vector_type(8)));
typedef float f32x4 __attribute__((ext_vector_type(4)));
typedef unsigned short u16;

__device__ __forceinline__ u16 f2bf(float f) {
    unsigned int u = __float_as_uint(f);
    u += 0x7FFF + ((u >> 16) & 1); // RNE
    return (u16)(u >> 16);
}

// async global->LDS, 16B per lane. LDS dest must be wave-uniform base + lane*16.
__device__ __forceinline__ void load_lds16(const u16* g, u16* lds) {
    __builtin_amdgcn_global_load_lds(
        (const __attribute__((address_space(1))) unsigned int*)(uintptr_t)g,
        (__attribute__((address_space(3))) unsigned int*)(unsigned int)(uintptr_t)lds,
        16, 0, 0);
}

// ---------------- cast x fp32 -> bf16 ----------------
__global__ __launch_bounds__(256) void cast_x_kernel(const float* __restrict__ in,
                                                     u16* __restrict__ out) {
    int i = (blockIdx.x * 256 + threadIdx.x) * 4;
    float4 v = *(const float4*)(in + i);
    ushort4 o;
    o.x = f2bf(v.x); o.y = f2bf(v.y); o.z = f2bf(v.z); o.w = f2bf(v.w);
    *(ushort4*)(out + i) = o;
}

// ---------------- transpose+cast the 4 weight matrices: W[K][N] fp32 -> Wt[N][K] bf16 ----------------
__global__ __launch_bounds__(256) void transpose_w_kernel(
    const float* __restrict__ w0, const float* __restrict__ w1,
    const float* __restrict__ w2, const float* __restrict__ w3,
    u16* __restrict__ o0, u16* __restrict__ o1,
    u16* __restrict__ o2, u16* __restrict__ o3) {
    __shared__ u16 tile[64][72]; // +8 pad breaks bank alignment on transposed reads
    int z = blockIdx.z;
    const float* in = z == 0 ? w0 : z == 1 ? w1 : z == 2 ? w2 : w3;
    u16* out = z == 0 ? o0 : z == 1 ? o1 : z == 2 ? o2 : o3;
    int r0 = blockIdx.y * 64, c0 = blockIdx.x * 64;
    int t = threadIdx.x;
#pragma unroll
    for (int i = 0; i < 16; ++i) {
        int idx = i * 256 + t;
        int r = idx >> 6, c = idx & 63;
        tile[r][c] = f2bf(in[(size_t)(r0 + r) * DIM + c0 + c]);
    }
    __syncthreads();
#pragma unroll
    for (int i = 0; i < 16; ++i) {
        int idx = i * 256 + t;
        int r = idx >> 6, c = idx & 63;
        out[(size_t)(c0 + r) * DIM + r0 + c] = tile[c][r];
    }
}

// ---------------- transpose V bf16 [B*S][D] -> Vt bf16 [B][H][hd][S] ----------------
__global__ __launch_bounds__(256) void transpose_v_kernel(const u16* __restrict__ V,
                                                          u16* __restrict__ Vt) {
    __shared__ u16 tile[64][72];
    int s0 = blockIdx.x * 64, d0 = blockIdx.y * 64;
    int bh = blockIdx.z;
    int b = bh >> 4, h = bh & 15;
    int t = threadIdx.x;
#pragma unroll
    for (int i = 0; i < 16; ++i) {
        int idx = i * 256 + t;
        int r = idx >> 6, c = idx & 63;
        tile[r][c] = V[((size_t)(b * SQ_S + s0 + r)) * DIM + h * HD + d0 + c];
    }
    __syncthreads();
#pragma unroll
    for (int i = 0; i < 16; ++i) {
        int idx = i * 256 + t;
        int r = idx >> 6, c = idx & 63;
        Vt[((size_t)(bh * HD + d0 + r)) * SQ_S + s0 + c] = tile[c][r];
    }
}

// ---------------- GEMM: C[M][N] = A[M][K] x Bt[N][K]^T, bf16 in, bf16 out ----------------
// 128x128 tile, BK=64, 4 waves each computing 64x64 via 4x4 MFMA 16x16x32 frags.
__global__ __launch_bounds__(256) void gemm_bt_bf16(const u16* __restrict__ A,
                                                    const u16* __restrict__ Bt,
                                                    u16* __restrict__ C,
                                                    int M, int N, int K) {
    __shared__ u16 As[128 * 64];
    __shared__ u16 Bs[128 * 64];
    int t = threadIdx.x;
    int w = t >> 6, l = t & 63;
    int wm = (w >> 1) * 64, wn = (w & 1) * 64;
    int lr = l & 15, lk = (l >> 4) * 8;
    int bm = blockIdx.y, bn = blockIdx.x;
    f32x4 acc[4][4] = {};

    for (int k0 = 0; k0 < K; k0 += 64) {
        __syncthreads();
#pragma unroll
        for (int c = 0; c < 4; ++c) {
            int e = c * 2048 + t * 8;
            int row = e >> 6, col = e & 63;
            load_lds16(A + (size_t)(bm * 128 + row) * K + k0 + col, As + e);
        }
#pragma unroll
        for (int c = 0; c < 4; ++c) {
            int e = c * 2048 + t * 8;
            int row = e >> 6, col = e & 63;
            load_lds16(Bt + (size_t)(bn * 128 + row) * K + k0 + col, Bs + e);
        }
        __syncthreads();
#pragma unroll
        for (int kk = 0; kk < 2; ++kk) {
            bf16x8 a[4], b[4];
#pragma unroll
            for (int mt = 0; mt < 4; ++mt)
                a[mt] = *(const bf16x8*)(As + (wm + mt * 16 + lr) * 64 + kk * 32 + lk);
#pragma unroll
            for (int nt = 0; nt < 4; ++nt)
                b[nt] = *(const bf16x8*)(Bs + (wn + nt * 16 + lr) * 64 + kk * 32 + lk);
#pragma unroll
            for (int mt = 0; mt < 4; ++mt)
#pragma unroll
                for (int nt = 0; nt < 4; ++nt)
                    acc[mt][nt] = __builtin_amdgcn_mfma_f32_16x16x32_bf16(a[mt], b[nt], acc[mt][nt], 0, 0, 0);
        }
    }
    // epilogue: C/D layout row=(l>>4)*4+r, col=l&15
    int r0 = bm * 128 + wm, c0 = bn * 128 + wn;
#pragma unroll
    for (int mt = 0; mt < 4; ++mt)
#pragma unroll
        for (int nt = 0; nt < 4; ++nt)
#pragma unroll
            for (int r = 0; r < 4; ++r) {
                int row = r0 + mt * 16 + (l >> 4) * 4 + r;
                int col = c0 + nt * 16 + lr;
                C[(size_t)row * N + col] = f2bf(acc[mt][nt][r]);
            }
}

// ---------------- GEMM variant: fp32 out + bias (final projection) ----------------
__global__ __launch_bounds__(256) void gemm_bt_f32b(const u16* __restrict__ A,
                                                    const u16* __restrict__ Bt,
                                                    float* __restrict__ C,
                                                    const float* __restrict__ bias,
                                                    int M, int N, int K) {
    __shared__ u16 As[128 * 64];
    __shared__ u16 Bs[128 * 64];
    int t = threadIdx.x;
    int w = t >> 6, l = t & 63;
    int wm = (w >> 1) * 64, wn = (w & 1) * 64;
    int lr = l & 15, lk = (l >> 4) * 8;
    int bm = blockIdx.y, bn = blockIdx.x;
    f32x4 acc[4][4] = {};

    for (int k0 = 0; k0 < K; k0 += 64) {
        __syncthreads();
#pragma unroll
        for (int c = 0; c < 4; ++c) {
            int e = c * 2048 + t * 8;
            int row = e >> 6, col = e & 63;
            load_lds16(A + (size_t)(bm * 128 + row) * K + k0 + col, As + e);
        }
#pragma unroll
        for (int c = 0; c < 4; ++c) {
            int e = c * 2048 + t * 8;
            int row = e >> 6, col = e & 63;
            load_lds16(Bt + (size_t)(bn * 128 + row) * K + k0 + col, Bs + e);
        }
        __syncthreads();
#pragma unroll
        for (int kk = 0; kk < 2; ++kk) {
            bf16x8 a[4], b[4];
#pragma unroll
            for (int mt = 0; mt < 4; ++mt)
                a[mt] = *(const bf16x8*)(As + (wm + mt * 16 + lr) * 64 + kk * 32 + lk);
#pragma unroll
            for (int nt = 0; nt < 4; ++nt)
                b[nt] = *(const bf16x8*)(Bs + (wn + nt * 16 + lr) * 64 + kk * 32 + lk);
#pragma unroll
            for (int mt = 0; mt < 4; ++mt)
#pragma unroll
                for (int nt = 0; nt < 4; ++nt)
                    acc[mt][nt] = __builtin_amdgcn_mfma_f32_16x16x32_bf16(a[mt], b[nt], acc[mt][nt], 0, 0, 0);
        }
    }
    int r0 = bm * 128 + wm, c0 = bn * 128 + wn;
#pragma unroll
    for (int mt = 0; mt < 4; ++mt)
#pragma unroll
        for (int nt = 0; nt < 4; ++nt)
#pragma unroll
            for (int r = 0; r < 4; ++r) {
                int row = r0 + mt * 16 + (l >> 4) * 4 + r;
                int col = c0 + nt * 16 + lr;
                C[(size_t)row * N + col] = acc[mt][nt][r] + bias[col];
            }
}

// ---------------- causal flash attention ----------------
// Q,K: bf16 [B*S][D] (head h in cols h*HD..h*HD+127); Vt: bf16 [B][H][hd][S];
// ctx out: bf16 [B*S][D]. Block = 256 threads (4 waves), BQ=64 (16 q-rows/wave), BJ=64.
__global__ __launch_bounds__(256) void attn_kernel(const u16* __restrict__ Q,
                                                   const u16* __restrict__ K,
                                                   const u16* __restrict__ Vt,
                                                   u16* __restrict__ ctx) {
    __shared__ u16 Kl[64 * 128];   // [j][d]
    __shared__ u16 Vl[128 * 64];   // [d][j] (pre-transposed V)
    __shared__ u16 Pl[4][16 * 64]; // per-wave P round-trip [q][j]
    int t = threadIdx.x;
    int w = t >> 6, l = t & 63;
    int lr = l & 15, lk = (l >> 4) * 8;
    int qt = blockIdx.x, h = blockIdx.y, b = blockIdx.z;
    int q0 = qt * 64;
    const float scale = 0.08838834764831845f; // 1/sqrt(128)

    // Q fragments resident in registers: wave w handles q-rows q0+w*16 .. +15
    bf16x8 qf[4];
    {
        const u16* qp = Q + ((size_t)(b * SQ_S + q0 + w * 16 + lr)) * DIM + h * HD;
#pragma unroll
        for (int kd = 0; kd < 4; ++kd)
            qf[kd] = *(const bf16x8*)(qp + kd * 32 + lk);
    }

    f32x4 o[8] = {};
    float m_r[4], l_r[4];
#pragma unroll
    for (int r = 0; r < 4; ++r) { m_r[r] = -3.0e38f; l_r[r] = 0.f; }

    int njt = qt + 1; // causal: only tiles with j0 <= q0
    for (int jt = 0; jt < njt; ++jt) {
        int j0 = jt * 64;
        __syncthreads();
        // stage K tile [64][128]
#pragma unroll
        for (int c = 0; c < 4; ++c) {
            int e = c * 2048 + t * 8;
            int row = e >> 7, col = e & 127;
            load_lds16(K + ((size_t)(b * SQ_S + j0 + row)) * DIM + h * HD + col, Kl + e);
        }
        // stage Vt tile [128][64]
#pragma unroll
        for (int c = 0; c < 4; ++c) {
            int e = c * 2048 + t * 8;
            int row = e >> 6, col = e & 63;
            load_lds16(Vt + ((size_t)((b * NH + h) * HD + row)) * SQ_S + j0 + col, Vl + e);
        }
        __syncthreads();

        // S = Q K^T for this wave's 16 q-rows x 64 j-cols
        f32x4 s[4] = {};
#pragma unroll
        for (int kd = 0; kd < 4; ++kd) {
#pragma unroll
            for (int nt = 0; nt < 4; ++nt) {
                bf16x8 kb = *(const bf16x8*)(Kl + (nt * 16 + lr) * 128 + kd * 32 + lk);
                s[nt] = __builtin_amdgcn_mfma_f32_16x16x32_bf16(qf[kd], kb, s[nt], 0, 0, 0);
            }
        }
        float sv[4][4];
        bool diag = (jt == njt - 1); // j0 == q0 tile needs masking
#pragma unroll
        for (int nt = 0; nt < 4; ++nt)
#pragma unroll
            for (int r = 0; r < 4; ++r) {
                float v = s[nt][r] * scale;
                // C layout: q_local = w*16 + (l>>4)*4 + r, j_local = nt*16 + lr
                if (diag && (nt * 16 + lr > w * 16 + (l >> 4) * 4 + r)) v = -3.0e38f;
                sv[nt][r] = v;
            }
        // row max across 64 j (4 frags local + 16 lanes of the quad-group)
        float mx[4];
#pragma unroll
        for (int r = 0; r < 4; ++r)
            mx[r] = fmaxf(fmaxf(sv[0][r], sv[1][r]), fmaxf(sv[2][r], sv[3][r]));
#pragma unroll
        for (int d = 1; d < 16; d <<= 1)
#pragma unroll
            for (int r = 0; r < 4; ++r)
                mx[r] = fmaxf(mx[r], __shfl_xor(mx[r], d, 64));
        float al[4];
#pragma unroll
        for (int r = 0; r < 4; ++r) {
            float mn = fmaxf(m_r[r], mx[r]);
            al[r] = __expf(m_r[r] - mn);
            m_r[r] = mn;
        }
        // P = exp(s - m), row sums
        float rs[4] = {0.f, 0.f, 0.f, 0.f};
        float pv[4][4];
#pragma unroll
        for (int nt = 0; nt < 4; ++nt)
#pragma unroll
            for (int r = 0; r < 4; ++r) {
                float p = __expf(sv[nt][r] - m_r[r]);
                pv[nt][r] = p;
                rs[r] += p;
            }
#pragma unroll
        for (int d = 1; d < 16; d <<= 1)
#pragma unroll
            for (int r = 0; r < 4; ++r)
                rs[r] += __shfl_xor(rs[r], d, 64);
#pragma unroll
        for (int r = 0; r < 4; ++r)
            l_r[r] = l_r[r] * al[r] + rs[r];
        // rescale O
#pragma unroll
        for (int nd = 0; nd < 8; ++nd)
#pragma unroll
            for (int r = 0; r < 4; ++r)
                o[nd][r] *= al[r];
        // P: C-layout regs -> LDS -> A-fragment layout (per-wave buffer, intra-wave sync)
        u16* pw = Pl[w];
#pragma unroll
        for (int nt = 0; nt < 4; ++nt)
#pragma unroll
            for (int r = 0; r < 4; ++r)
                pw[((l >> 4) * 4 + r) * 64 + nt * 16 + lr] = f2bf(pv[nt][r]);
        asm volatile("s_waitcnt lgkmcnt(0)" ::: "memory");
        // O += P V
#pragma unroll
        for (int kj = 0; kj < 2; ++kj) {
            bf16x8 pa = *(const bf16x8*)(pw + lr * 64 + kj * 32 + lk);
#pragma unroll
            for (int nd = 0; nd < 8; ++nd) {
                bf16x8 vb = *(const bf16x8*)(Vl + (nd * 16 + lr) * 64 + kj * 32 + lk);
                o[nd] = __builtin_amdgcn_mfma_f32_16x16x32_bf16(pa, vb, o[nd], 0, 0, 0);
            }
        }
    }
    // epilogue: ctx[b*S+q][h*HD+d] = O / l
#pragma unroll
    for (int r = 0; r < 4; ++r) l_r[r] = 1.f / l_r[r];
#pragma unroll
    for (int nd = 0; nd < 8; ++nd)
#pragma unroll
        for (int r = 0; r < 4; ++r) {
            int row = q0 + w * 16 + (l >> 4) * 4 + r;
            int col = h * HD + nd * 16 + lr;
            ctx[((size_t)(b * SQ_S + row)) * DIM + col] = f2bf(o[nd][r] * l_r[r]);
        }
}

extern "C" void kernel_launch(void* const* d_in, const int* in_sizes, int n_in,
                              void* d_out, int out_size, void* d_ws, size_t ws_size,
                              hipStream_t stream) {
    const float* x  = (const float*)d_in[0];
    const float* Wq = (const float*)d_in[1];
    const float* Wk = (const float*)d_in[2];
    const float* Wv = (const float*)d_in[3];
    const float* Wo = (const float*)d_in[4];
    const float* bo = (const float*)d_in[5];
    float* out = (float*)d_out;

    char* p = (char*)d_ws;
    const size_t SZ_ACT = (size_t)NROWS * DIM * 2; // 16 MB
    const size_t SZ_W   = (size_t)DIM * DIM * 2;   // 8 MB
    u16* Xb  = (u16*)(p);
    u16* Wqt = (u16*)(p + SZ_ACT);
    u16* Wkt = (u16*)(p + SZ_ACT + 1 * SZ_W);
    u16* Wvt = (u16*)(p + SZ_ACT + 2 * SZ_W);
    u16* Wot = (u16*)(p + SZ_ACT + 3 * SZ_W);
    u16* Qm  = (u16*)(p + 1 * SZ_ACT + 4 * SZ_W);
    u16* Km  = (u16*)(p + 2 * SZ_ACT + 4 * SZ_W);
    u16* Vm  = (u16*)(p + 3 * SZ_ACT + 4 * SZ_W);
    u16* Vt  = (u16*)(p + 4 * SZ_ACT + 4 * SZ_W);
    u16* Cx  = (u16*)(p + 5 * SZ_ACT + 4 * SZ_W);
    // total ws use: 5*16MB + 4*8MB = 112 MB... +16MB Cx = 128 MB

    cast_x_kernel<<<(NROWS * DIM) / 1024, 256, 0, stream>>>(x, Xb);
    transpose_w_kernel<<<dim3(DIM / 64, DIM / 64, 4), 256, 0, stream>>>(
        Wq, Wk, Wv, Wo, Wqt, Wkt, Wvt, Wot);
    gemm_bt_bf16<<<dim3(DIM / 128, NROWS / 128), 256, 0, stream>>>(Xb, Wqt, Qm, NROWS, DIM, DIM);
    gemm_bt_bf16<<<dim3(DIM / 128, NROWS / 128), 256, 0, stream>>>(Xb, Wkt, Km, NROWS, DIM, DIM);
    gemm_bt_bf16<<<dim3(DIM / 128, NROWS / 128), 256, 0, stream>>>(Xb, Wvt, Vm, NROWS, DIM, DIM);
    transpose_v_kernel<<<dim3(SQ_S / 64, HD / 64, NB * NH), 256, 0, stream>>>(Vm, Vt);
    attn_kernel<<<dim3(SQ_S / 64, NH, NB), 256, 0, stream>>>(Qm, Km, Vt, Cx);
    gemm_bt_f32b<<<dim3(DIM / 128, NROWS / 128), 256, 0, stream>>>(Cx, Wot, out, bo, NROWS, DIM, DIM);
}

// Round 2
// 477.254 us; speedup vs baseline: 1.3071x; 1.3071x over previous
//
#include <hip/hip_runtime.h>
#include <stdint.h>

// Problem constants (fixed by the reference: B=2, S=2048, D=2048, H=16)
#define SQ_S 2048
#define DIM 2048
#define NH 16
#define HD 128
#define NB 2
#define NROWS (NB * SQ_S) // 4096
#define NQKV (3 * DIM)    // 6144 fused QKV output width

typedef __bf16 bf16x8 __attribute__((ext_vector_type(8)));
typedef float f32x4 __attribute__((ext_vector_type(4)));
typedef unsigned short u16;

__device__ __forceinline__ u16 f2bf(float f) {
    unsigned int u = __float_as_uint(f);
    u += 0x7FFF + ((u >> 16) & 1); // RNE
    return (u16)(u >> 16);
}

// async global->LDS, 16B per lane. LDS dest must be wave-uniform base + lane*16.
// Per-lane GLOBAL addresses are fine (normal vector load semantics).
__device__ __forceinline__ void load_lds16(const u16* g, u16* lds) {
    __builtin_amdgcn_global_load_lds(
        (const __attribute__((address_space(1))) unsigned int*)(uintptr_t)g,
        (__attribute__((address_space(3))) unsigned int*)(unsigned int)(uintptr_t)lds,
        16, 0, 0);
}

// ---------------- cast x fp32 -> bf16 ----------------
__global__ __launch_bounds__(256) void cast_x_kernel(const float* __restrict__ in,
                                                     u16* __restrict__ out) {
    int i = (blockIdx.x * 256 + threadIdx.x) * 4;
    float4 v = *(const float4*)(in + i);
    ushort4 o;
    o.x = f2bf(v.x); o.y = f2bf(v.y); o.z = f2bf(v.z); o.w = f2bf(v.w);
    *(ushort4*)(out + i) = o;
}

// ---------------- transpose+cast the 4 weight matrices: W[K][N] fp32 -> Wt[N][K] bf16 ----------------
__global__ __launch_bounds__(256) void transpose_w_kernel(
    const float* __restrict__ w0, const float* __restrict__ w1,
    const float* __restrict__ w2, const float* __restrict__ w3,
    u16* __restrict__ o0, u16* __restrict__ o1,
    u16* __restrict__ o2, u16* __restrict__ o3) {
    __shared__ u16 tile[64][72];
    int z = blockIdx.z;
    const float* in = z == 0 ? w0 : z == 1 ? w1 : z == 2 ? w2 : w3;
    u16* out = z == 0 ? o0 : z == 1 ? o1 : z == 2 ? o2 : o3;
    int r0 = blockIdx.y * 64, c0 = blockIdx.x * 64;
    int t = threadIdx.x;
#pragma unroll
    for (int i = 0; i < 16; ++i) {
        int idx = i * 256 + t;
        int r = idx >> 6, c = idx & 63;
        tile[r][c] = f2bf(in[(size_t)(r0 + r) * DIM + c0 + c]);
    }
    __syncthreads();
#pragma unroll
    for (int i = 0; i < 16; ++i) {
        int idx = i * 256 + t;
        int r = idx >> 6, c = idx & 63;
        out[(size_t)(c0 + r) * DIM + r0 + c] = tile[c][r];
    }
}

// ---------------- transpose V bf16 [B*S][ldv] (head slice) -> Vt bf16 [B][H][hd][S] ----------------
__global__ __launch_bounds__(256) void transpose_v_kernel(const u16* __restrict__ V,
                                                          u16* __restrict__ Vt, int ldv) {
    __shared__ u16 tile[64][72];
    int s0 = blockIdx.x * 64, d0 = blockIdx.y * 64;
    int bh = blockIdx.z;
    int b = bh >> 4, h = bh & 15;
    int t = threadIdx.x;
#pragma unroll
    for (int i = 0; i < 16; ++i) {
        int idx = i * 256 + t;
        int r = idx >> 6, c = idx & 63;
        tile[r][c] = V[((size_t)(b * SQ_S + s0 + r)) * ldv + h * HD + d0 + c];
    }
    __syncthreads();
#pragma unroll
    for (int i = 0; i < 16; ++i) {
        int idx = i * 256 + t;
        int r = idx >> 6, c = idx & 63;
        Vt[((size_t)(bh * HD + d0 + r)) * SQ_S + s0 + c] = tile[c][r];
    }
}

// ---------------- GEMM: C[M][N] = A[M][K] x Bt[N][K]^T, bf16 in, bf16 out ----------------
// 128x128 tile, BK=64, 4 waves each computing 64x64 via 4x4 MFMA 16x16x32 frags.
// LDS tiles [128 rows][64 u16] use XOR-swizzle: logical chunk c (8 u16) of row r
// stored at physical chunk c ^ (r & 7). Kills the 16-way ds_read_b128 conflicts.
__global__ __launch_bounds__(256) void gemm_bt_bf16(const u16* __restrict__ A,
                                                    const u16* __restrict__ Bt,
                                                    u16* __restrict__ C,
                                                    int M, int N, int K) {
    __shared__ u16 As[128 * 64];
    __shared__ u16 Bs[128 * 64];
    int t = threadIdx.x;
    int w = t >> 6, l = t & 63;
    int wm = (w >> 1) * 64, wn = (w & 1) * 64;
    int lr = l & 15, q = l >> 4;
    int bm = blockIdx.y, bn = blockIdx.x;
    // staging: lane t deposits to LDS offset t*8 (contiguous); global column is the
    // swizzle-inverse so that LDS[row][cp] = global chunk cp ^ (row&7)
    int st_gcol = (((t & 7) ^ ((t >> 3) & 7)) * 8);
    f32x4 acc[4][4] = {};

    for (int k0 = 0; k0 < K; k0 += 64) {
        __syncthreads();
#pragma unroll
        for (int c = 0; c < 4; ++c) {
            int e = c * 2048 + t * 8;
            int row = e >> 6;
            load_lds16(A + (size_t)(bm * 128 + row) * K + k0 + st_gcol, As + e);
        }
#pragma unroll
        for (int c = 0; c < 4; ++c) {
            int e = c * 2048 + t * 8;
            int row = e >> 6;
            load_lds16(Bt + (size_t)(bn * 128 + row) * K + k0 + st_gcol, Bs + e);
        }
        __syncthreads();
#pragma unroll
        for (int kk = 0; kk < 2; ++kk) {
            bf16x8 a[4], b[4];
#pragma unroll
            for (int mt = 0; mt < 4; ++mt)
                a[mt] = *(const bf16x8*)(As + (wm + mt * 16 + lr) * 64 +
                                         (((kk * 4 + q) ^ (lr & 7)) * 8));
#pragma unroll
            for (int nt = 0; nt < 4; ++nt)
                b[nt] = *(const bf16x8*)(Bs + (wn + nt * 16 + lr) * 64 +
                                         (((kk * 4 + q) ^ (lr & 7)) * 8));
#pragma unroll
            for (int mt = 0; mt < 4; ++mt)
#pragma unroll
                for (int nt = 0; nt < 4; ++nt)
                    acc[mt][nt] = __builtin_amdgcn_mfma_f32_16x16x32_bf16(a[mt], b[nt], acc[mt][nt], 0, 0, 0);
        }
    }
    // epilogue: C/D layout row=(l>>4)*4+r, col=l&15
    int r0 = bm * 128 + wm, c0 = bn * 128 + wn;
#pragma unroll
    for (int mt = 0; mt < 4; ++mt)
#pragma unroll
        for (int nt = 0; nt < 4; ++nt)
#pragma unroll
            for (int r = 0; r < 4; ++r) {
                int row = r0 + mt * 16 + q * 4 + r;
                int col = c0 + nt * 16 + lr;
                C[(size_t)row * N + col] = f2bf(acc[mt][nt][r]);
            }
}

// ---------------- GEMM variant: fp32 out + bias (final projection) ----------------
__global__ __launch_bounds__(256) void gemm_bt_f32b(const u16* __restrict__ A,
                                                    const u16* __restrict__ Bt,
                                                    float* __restrict__ C,
                                                    const float* __restrict__ bias,
                                                    int M, int N, int K) {
    __shared__ u16 As[128 * 64];
    __shared__ u16 Bs[128 * 64];
    int t = threadIdx.x;
    int w = t >> 6, l = t & 63;
    int wm = (w >> 1) * 64, wn = (w & 1) * 64;
    int lr = l & 15, q = l >> 4;
    int bm = blockIdx.y, bn = blockIdx.x;
    int st_gcol = (((t & 7) ^ ((t >> 3) & 7)) * 8);
    f32x4 acc[4][4] = {};

    for (int k0 = 0; k0 < K; k0 += 64) {
        __syncthreads();
#pragma unroll
        for (int c = 0; c < 4; ++c) {
            int e = c * 2048 + t * 8;
            int row = e >> 6;
            load_lds16(A + (size_t)(bm * 128 + row) * K + k0 + st_gcol, As + e);
        }
#pragma unroll
        for (int c = 0; c < 4; ++c) {
            int e = c * 2048 + t * 8;
            int row = e >> 6;
            load_lds16(Bt + (size_t)(bn * 128 + row) * K + k0 + st_gcol, Bs + e);
        }
        __syncthreads();
#pragma unroll
        for (int kk = 0; kk < 2; ++kk) {
            bf16x8 a[4], b[4];
#pragma unroll
            for (int mt = 0; mt < 4; ++mt)
                a[mt] = *(const bf16x8*)(As + (wm + mt * 16 + lr) * 64 +
                                         (((kk * 4 + q) ^ (lr & 7)) * 8));
#pragma unroll
            for (int nt = 0; nt < 4; ++nt)
                b[nt] = *(const bf16x8*)(Bs + (wn + nt * 16 + lr) * 64 +
                                         (((kk * 4 + q) ^ (lr & 7)) * 8));
#pragma unroll
            for (int mt = 0; mt < 4; ++mt)
#pragma unroll
                for (int nt = 0; nt < 4; ++nt)
                    acc[mt][nt] = __builtin_amdgcn_mfma_f32_16x16x32_bf16(a[mt], b[nt], acc[mt][nt], 0, 0, 0);
        }
    }
    int r0 = bm * 128 + wm, c0 = bn * 128 + wn;
#pragma unroll
    for (int mt = 0; mt < 4; ++mt)
#pragma unroll
        for (int nt = 0; nt < 4; ++nt)
#pragma unroll
            for (int r = 0; r < 4; ++r) {
                int row = r0 + mt * 16 + q * 4 + r;
                int col = c0 + nt * 16 + lr;
                C[(size_t)row * N + col] = acc[mt][nt][r] + bias[col];
            }
}

// ---------------- causal flash attention ----------------
// Q,K: bf16 [B*S][ldqk] (head h at cols h*HD..+127); Vt: bf16 [B][H][hd][S];
// ctx out: bf16 [B*S][DIM]. Block = 256 threads (4 waves), BQ=64 (16 q-rows/wave), BJ=64.
// All LDS tiles XOR-swizzled (chunk ^ row&7, or &15 for the 128-u16 K rows).
__global__ __launch_bounds__(256) void attn_kernel(const u16* __restrict__ Q,
                                                   const u16* __restrict__ K,
                                                   const u16* __restrict__ Vt,
                                                   u16* __restrict__ ctx, int ldqk) {
    __shared__ u16 Kl[64 * 128];   // [j][d], 16 chunks/row, swizzle ^ (row&15)
    __shared__ u16 Vl[128 * 64];   // [d][j], 8 chunks/row, swizzle ^ (row&7)
    __shared__ u16 Pl[4][16 * 64]; // per-wave P round-trip, swizzle ^ (row&7)
    int t = threadIdx.x;
    int w = t >> 6, l = t & 63;
    int lr = l & 15, q = l >> 4, lk = q * 8;
    int qt = blockIdx.x, h = blockIdx.y, b = blockIdx.z;
    int q0 = qt * 64;
    const float scale = 0.08838834764831845f; // 1/sqrt(128)
    // staging swizzle-inverse global columns
    int stK_gcol = (((t & 15) ^ (t >> 4)) * 8);          // K: 16 chunks per 128-u16 row
    int stV_gcol = (((t & 7) ^ ((t >> 3) & 7)) * 8);     // V: 8 chunks per 64-u16 row

    // Q fragments resident in registers: wave w handles q-rows q0+w*16 .. +15
    bf16x8 qf[4];
    {
        const u16* qp = Q + ((size_t)(b * SQ_S + q0 + w * 16 + lr)) * ldqk + h * HD;
#pragma unroll
        for (int kd = 0; kd < 4; ++kd)
            qf[kd] = *(const bf16x8*)(qp + kd * 32 + lk);
    }

    f32x4 o[8] = {};
    float m_r[4], l_r[4];
#pragma unroll
    for (int r = 0; r < 4; ++r) { m_r[r] = -3.0e38f; l_r[r] = 0.f; }

    int njt = qt + 1; // causal: only tiles with j0 <= q0
    for (int jt = 0; jt < njt; ++jt) {
        int j0 = jt * 64;
        __syncthreads();
        // stage K tile [64][128]
#pragma unroll
        for (int c = 0; c < 4; ++c) {
            int e = c * 2048 + t * 8;
            int row = e >> 7;
            load_lds16(K + ((size_t)(b * SQ_S + j0 + row)) * ldqk + h * HD + stK_gcol, Kl + e);
        }
        // stage Vt tile [128][64]
#pragma unroll
        for (int c = 0; c < 4; ++c) {
            int e = c * 2048 + t * 8;
            int row = e >> 6;
            load_lds16(Vt + ((size_t)((b * NH + h) * HD + row)) * SQ_S + j0 + stV_gcol, Vl + e);
        }
        __syncthreads();

        // S = Q K^T for this wave's 16 q-rows x 64 j-cols
        f32x4 s[4] = {};
#pragma unroll
        for (int kd = 0; kd < 4; ++kd) {
#pragma unroll
            for (int nt = 0; nt < 4; ++nt) {
                bf16x8 kb = *(const bf16x8*)(Kl + (nt * 16 + lr) * 128 +
                                             (((kd * 4 + q) ^ lr) * 8));
                s[nt] = __builtin_amdgcn_mfma_f32_16x16x32_bf16(qf[kd], kb, s[nt], 0, 0, 0);
            }
        }
        float sv[4][4];
        bool diag = (jt == njt - 1); // j0 == q0 tile needs masking
#pragma unroll
        for (int nt = 0; nt < 4; ++nt)
#pragma unroll
            for (int r = 0; r < 4; ++r) {
                float v = s[nt][r] * scale;
                // C layout: q_local = w*16 + q*4 + r, j_local = nt*16 + lr
                if (diag && (nt * 16 + lr > w * 16 + q * 4 + r)) v = -3.0e38f;
                sv[nt][r] = v;
            }
        // row max across 64 j (4 frags local + 16 lanes of the group)
        float mx[4];
#pragma unroll
        for (int r = 0; r < 4; ++r)
            mx[r] = fmaxf(fmaxf(sv[0][r], sv[1][r]), fmaxf(sv[2][r], sv[3][r]));
#pragma unroll
        for (int d = 1; d < 16; d <<= 1)
#pragma unroll
            for (int r = 0; r < 4; ++r)
                mx[r] = fmaxf(mx[r], __shfl_xor(mx[r], d, 64));
        float al[4];
#pragma unroll
        for (int r = 0; r < 4; ++r) {
            float mn = fmaxf(m_r[r], mx[r]);
            al[r] = __expf(m_r[r] - mn);
            m_r[r] = mn;
        }
        // P = exp(s - m), row sums
        float rs[4] = {0.f, 0.f, 0.f, 0.f};
        float pv[4][4];
#pragma unroll
        for (int nt = 0; nt < 4; ++nt)
#pragma unroll
            for (int r = 0; r < 4; ++r) {
                float p = __expf(sv[nt][r] - m_r[r]);
                pv[nt][r] = p;
                rs[r] += p;
            }
#pragma unroll
        for (int d = 1; d < 16; d <<= 1)
#pragma unroll
            for (int r = 0; r < 4; ++r)
                rs[r] += __shfl_xor(rs[r], d, 64);
#pragma unroll
        for (int r = 0; r < 4; ++r)
            l_r[r] = l_r[r] * al[r] + rs[r];
        // rescale O
#pragma unroll
        for (int nd = 0; nd < 8; ++nd)
#pragma unroll
            for (int r = 0; r < 4; ++r)
                o[nd][r] *= al[r];
        // P: C-layout regs -> LDS -> A-fragment layout (per-wave buffer, intra-wave sync)
        // logical (row=q*4+r, col=nt*16+lr) -> offset row*64 + ((col>>3)^(row&7))*8 + (col&7)
        u16* pw = Pl[w];
#pragma unroll
        for (int nt = 0; nt < 4; ++nt)
#pragma unroll
            for (int r = 0; r < 4; ++r) {
                int prow = q * 4 + r;
                int pcol = nt * 16 + lr;
                pw[prow * 64 + (((pcol >> 3) ^ (prow & 7)) * 8) + (pcol & 7)] = f2bf(pv[nt][r]);
            }
        asm volatile("s_waitcnt lgkmcnt(0)" ::: "memory");
        // O += P V  (A-frag read: row=lr, chunk kj*4+q, swizzled)
#pragma unroll
        for (int kj = 0; kj < 2; ++kj) {
            bf16x8 pa = *(const bf16x8*)(pw + lr * 64 + (((kj * 4 + q) ^ (lr & 7)) * 8));
#pragma unroll
            for (int nd = 0; nd < 8; ++nd) {
                bf16x8 vb = *(const bf16x8*)(Vl + (nd * 16 + lr) * 64 +
                                             (((kj * 4 + q) ^ (lr & 7)) * 8));
                o[nd] = __builtin_amdgcn_mfma_f32_16x16x32_bf16(pa, vb, o[nd], 0, 0, 0);
            }
        }
    }
    // epilogue: ctx[b*S+q][h*HD+d] = O / l
#pragma unroll
    for (int r = 0; r < 4; ++r) l_r[r] = 1.f / l_r[r];
#pragma unroll
    for (int nd = 0; nd < 8; ++nd)
#pragma unroll
        for (int r = 0; r < 4; ++r) {
            int row = q0 + w * 16 + q * 4 + r;
            int col = h * HD + nd * 16 + lr;
            ctx[((size_t)(b * SQ_S + row)) * DIM + col] = f2bf(o[nd][r] * l_r[r]);
        }
}

extern "C" void kernel_launch(void* const* d_in, const int* in_sizes, int n_in,
                              void* d_out, int out_size, void* d_ws, size_t ws_size,
                              hipStream_t stream) {
    const float* x  = (const float*)d_in[0];
    const float* Wq = (const float*)d_in[1];
    const float* Wk = (const float*)d_in[2];
    const float* Wv = (const float*)d_in[3];
    const float* Wo = (const float*)d_in[4];
    const float* bo = (const float*)d_in[5];
    float* out = (float*)d_out;

    char* p = (char*)d_ws;
    const size_t SZ_ACT  = (size_t)NROWS * DIM * 2;  // 16 MB
    const size_t SZ_W    = (size_t)DIM * DIM * 2;    // 8 MB
    const size_t SZ_QKV  = (size_t)NROWS * NQKV * 2; // 48 MB
    u16* Xb   = (u16*)(p);                                  // 16 MB
    u16* Wqkv = (u16*)(p + SZ_ACT);                         // 24 MB (Wq^T,Wk^T,Wv^T contiguous)
    u16* Wot  = (u16*)(p + SZ_ACT + 3 * SZ_W);              // 8 MB
    u16* QKV  = (u16*)(p + SZ_ACT + 4 * SZ_W);              // 48 MB
    u16* Vt   = (u16*)(p + SZ_ACT + 4 * SZ_W + SZ_QKV);     // 16 MB
    u16* Cx   = (u16*)(p + 2 * SZ_ACT + 4 * SZ_W + SZ_QKV); // 16 MB  (total 128 MB)

    cast_x_kernel<<<(NROWS * DIM) / 1024, 256, 0, stream>>>(x, Xb);
    transpose_w_kernel<<<dim3(DIM / 64, DIM / 64, 4), 256, 0, stream>>>(
        Wq, Wk, Wv, Wo,
        Wqkv, Wqkv + (size_t)DIM * DIM, Wqkv + 2 * (size_t)DIM * DIM, Wot);
    // fused QKV projection: [4096 x 2048] x [6144 x 2048]^T -> [4096 x 6144]
    gemm_bt_bf16<<<dim3(NQKV / 128, NROWS / 128), 256, 0, stream>>>(Xb, Wqkv, QKV, NROWS, NQKV, DIM);
    transpose_v_kernel<<<dim3(SQ_S / 64, HD / 64, NB * NH), 256, 0, stream>>>(QKV + 2 * DIM, Vt, NQKV);
    attn_kernel<<<dim3(SQ_S / 64, NH, NB), 256, 0, stream>>>(QKV, QKV + DIM, Vt, Cx, NQKV);
    gemm_bt_f32b<<<dim3(DIM / 128, NROWS / 128), 256, 0, stream>>>(Cx, Wot, out, bo, NROWS, DIM, DIM);
}

// Round 3
// 403.657 us; speedup vs baseline: 1.5454x; 1.1823x over previous
//
#include <hip/hip_runtime.h>
#include <stdint.h>

// Problem constants (fixed by the reference: B=2, S=2048, D=2048, H=16)
#define SQ_S 2048
#define DIM 2048
#define NH 16
#define HD 128
#define NB 2
#define NROWS (NB * SQ_S) // 4096
#define NQKV (3 * DIM)    // 6144 fused QKV output width

typedef __bf16 bf16x8 __attribute__((ext_vector_type(8)));
typedef float f32x4 __attribute__((ext_vector_type(4)));
typedef unsigned short u16;

__device__ __forceinline__ u16 f2bf(float f) {
    unsigned int u = __float_as_uint(f);
    u += 0x7FFF + ((u >> 16) & 1); // RNE
    return (u16)(u >> 16);
}

// async global->LDS, 16B per lane. LDS dest must be wave-uniform base + lane*16.
__device__ __forceinline__ void load_lds16(const u16* g, u16* lds) {
    __builtin_amdgcn_global_load_lds(
        (const __attribute__((address_space(1))) unsigned int*)(uintptr_t)g,
        (__attribute__((address_space(3))) unsigned int*)(unsigned int)(uintptr_t)lds,
        16, 0, 0);
}

// ---------------- cast x fp32 -> bf16 ----------------
__global__ __launch_bounds__(256) void cast_x_kernel(const float* __restrict__ in,
                                                     u16* __restrict__ out) {
    int i = (blockIdx.x * 256 + threadIdx.x) * 4;
    float4 v = *(const float4*)(in + i);
    ushort4 o;
    o.x = f2bf(v.x); o.y = f2bf(v.y); o.z = f2bf(v.z); o.w = f2bf(v.w);
    *(ushort4*)(out + i) = o;
}

// ---------------- transpose+cast the 4 weight matrices: W[K][N] fp32 -> Wt[N][K] bf16 ----------------
__global__ __launch_bounds__(256) void transpose_w_kernel(
    const float* __restrict__ w0, const float* __restrict__ w1,
    const float* __restrict__ w2, const float* __restrict__ w3,
    u16* __restrict__ o0, u16* __restrict__ o1,
    u16* __restrict__ o2, u16* __restrict__ o3) {
    __shared__ u16 tile[64][72];
    int z = blockIdx.z;
    const float* in = z == 0 ? w0 : z == 1 ? w1 : z == 2 ? w2 : w3;
    u16* out = z == 0 ? o0 : z == 1 ? o1 : z == 2 ? o2 : o3;
    int r0 = blockIdx.y * 64, c0 = blockIdx.x * 64;
    int t = threadIdx.x;
#pragma unroll
    for (int i = 0; i < 16; ++i) {
        int idx = i * 256 + t;
        int r = idx >> 6, c = idx & 63;
        tile[r][c] = f2bf(in[(size_t)(r0 + r) * DIM + c0 + c]);
    }
    __syncthreads();
#pragma unroll
    for (int i = 0; i < 16; ++i) {
        int idx = i * 256 + t;
        int r = idx >> 6, c = idx & 63;
        out[(size_t)(c0 + r) * DIM + r0 + c] = tile[c][r];
    }
}

// ---------------- transpose V bf16 [B*S][ldv] (head slice) -> Vt bf16 [B][H][hd][S] ----------------
__global__ __launch_bounds__(256) void transpose_v_kernel(const u16* __restrict__ V,
                                                          u16* __restrict__ Vt, int ldv) {
    __shared__ u16 tile[64][72];
    int s0 = blockIdx.x * 64, d0 = blockIdx.y * 64;
    int bh = blockIdx.z;
    int b = bh >> 4, h = bh & 15;
    int t = threadIdx.x;
#pragma unroll
    for (int i = 0; i < 16; ++i) {
        int idx = i * 256 + t;
        int r = idx >> 6, c = idx & 63;
        tile[r][c] = V[((size_t)(b * SQ_S + s0 + r)) * ldv + h * HD + d0 + c];
    }
    __syncthreads();
#pragma unroll
    for (int i = 0; i < 16; ++i) {
        int idx = i * 256 + t;
        int r = idx >> 6, c = idx & 63;
        Vt[((size_t)(bh * HD + d0 + r)) * SQ_S + s0 + c] = tile[c][r];
    }
}

// ---------------- GEMM: C[M][N] = A[M][K] x Bt[N][K]^T, bf16 in, bf16 out ----------------
// 128x128 tile, BK=64, 4 waves each computing 64x64 via 4x4 MFMA 16x16x32 frags.
// LDS tiles XOR-swizzled (chunk ^ row&7) -> conflict-free ds_read_b128.
__global__ __launch_bounds__(256) void gemm_bt_bf16(const u16* __restrict__ A,
                                                    const u16* __restrict__ Bt,
                                                    u16* __restrict__ C,
                                                    int M, int N, int K) {
    __shared__ u16 As[128 * 64];
    __shared__ u16 Bs[128 * 64];
    int t = threadIdx.x;
    int w = t >> 6, l = t & 63;
    int wm = (w >> 1) * 64, wn = (w & 1) * 64;
    int lr = l & 15, q = l >> 4;
    int bm = blockIdx.y, bn = blockIdx.x;
    int st_gcol = (((t & 7) ^ ((t >> 3) & 7)) * 8);
    f32x4 acc[4][4] = {};

    for (int k0 = 0; k0 < K; k0 += 64) {
        __syncthreads();
#pragma unroll
        for (int c = 0; c < 4; ++c) {
            int e = c * 2048 + t * 8;
            int row = e >> 6;
            load_lds16(A + (size_t)(bm * 128 + row) * K + k0 + st_gcol, As + e);
        }
#pragma unroll
        for (int c = 0; c < 4; ++c) {
            int e = c * 2048 + t * 8;
            int row = e >> 6;
            load_lds16(Bt + (size_t)(bn * 128 + row) * K + k0 + st_gcol, Bs + e);
        }
        __syncthreads();
#pragma unroll
        for (int kk = 0; kk < 2; ++kk) {
            bf16x8 a[4], b[4];
#pragma unroll
            for (int mt = 0; mt < 4; ++mt)
                a[mt] = *(const bf16x8*)(As + (wm + mt * 16 + lr) * 64 +
                                         (((kk * 4 + q) ^ (lr & 7)) * 8));
#pragma unroll
            for (int nt = 0; nt < 4; ++nt)
                b[nt] = *(const bf16x8*)(Bs + (wn + nt * 16 + lr) * 64 +
                                         (((kk * 4 + q) ^ (lr & 7)) * 8));
#pragma unroll
            for (int mt = 0; mt < 4; ++mt)
#pragma unroll
                for (int nt = 0; nt < 4; ++nt)
                    acc[mt][nt] = __builtin_amdgcn_mfma_f32_16x16x32_bf16(a[mt], b[nt], acc[mt][nt], 0, 0, 0);
        }
    }
    int r0 = bm * 128 + wm, c0 = bn * 128 + wn;
#pragma unroll
    for (int mt = 0; mt < 4; ++mt)
#pragma unroll
        for (int nt = 0; nt < 4; ++nt)
#pragma unroll
            for (int r = 0; r < 4; ++r) {
                int row = r0 + mt * 16 + q * 4 + r;
                int col = c0 + nt * 16 + lr;
                C[(size_t)row * N + col] = f2bf(acc[mt][nt][r]);
            }
}

// ---------------- GEMM variant: fp32 out + bias (final projection) ----------------
__global__ __launch_bounds__(256) void gemm_bt_f32b(const u16* __restrict__ A,
                                                    const u16* __restrict__ Bt,
                                                    float* __restrict__ C,
                                                    const float* __restrict__ bias,
                                                    int M, int N, int K) {
    __shared__ u16 As[128 * 64];
    __shared__ u16 Bs[128 * 64];
    int t = threadIdx.x;
    int w = t >> 6, l = t & 63;
    int wm = (w >> 1) * 64, wn = (w & 1) * 64;
    int lr = l & 15, q = l >> 4;
    int bm = blockIdx.y, bn = blockIdx.x;
    int st_gcol = (((t & 7) ^ ((t >> 3) & 7)) * 8);
    f32x4 acc[4][4] = {};

    for (int k0 = 0; k0 < K; k0 += 64) {
        __syncthreads();
#pragma unroll
        for (int c = 0; c < 4; ++c) {
            int e = c * 2048 + t * 8;
            int row = e >> 6;
            load_lds16(A + (size_t)(bm * 128 + row) * K + k0 + st_gcol, As + e);
        }
#pragma unroll
        for (int c = 0; c < 4; ++c) {
            int e = c * 2048 + t * 8;
            int row = e >> 6;
            load_lds16(Bt + (size_t)(bn * 128 + row) * K + k0 + st_gcol, Bs + e);
        }
        __syncthreads();
#pragma unroll
        for (int kk = 0; kk < 2; ++kk) {
            bf16x8 a[4], b[4];
#pragma unroll
            for (int mt = 0; mt < 4; ++mt)
                a[mt] = *(const bf16x8*)(As + (wm + mt * 16 + lr) * 64 +
                                         (((kk * 4 + q) ^ (lr & 7)) * 8));
#pragma unroll
            for (int nt = 0; nt < 4; ++nt)
                b[nt] = *(const bf16x8*)(Bs + (wn + nt * 16 + lr) * 64 +
                                         (((kk * 4 + q) ^ (lr & 7)) * 8));
#pragma unroll
            for (int mt = 0; mt < 4; ++mt)
#pragma unroll
                for (int nt = 0; nt < 4; ++nt)
                    acc[mt][nt] = __builtin_amdgcn_mfma_f32_16x16x32_bf16(a[mt], b[nt], acc[mt][nt], 0, 0, 0);
        }
    }
    int r0 = bm * 128 + wm, c0 = bn * 128 + wn;
#pragma unroll
    for (int mt = 0; mt < 4; ++mt)
#pragma unroll
        for (int nt = 0; nt < 4; ++nt)
#pragma unroll
            for (int r = 0; r < 4; ++r) {
                int row = r0 + mt * 16 + q * 4 + r;
                int col = c0 + nt * 16 + lr;
                C[(size_t)row * N + col] = acc[mt][nt][r] + bias[col];
            }
}

// ---------------- causal flash attention, load-balanced + double-buffered ----------------
// Block px handles q-tiles {px, 31-px}: every block does exactly 33 j-tile iterations.
// Grid = dim3(16, NH, NB) = 512 uniform blocks = 2/CU (LDS 72KB -> 2 blocks/CU).
// K/V LDS double-buffered: tile jt+1 is issued before compute of jt.
__global__ __launch_bounds__(256) void attn_kernel(const u16* __restrict__ Q,
                                                   const u16* __restrict__ K,
                                                   const u16* __restrict__ Vt,
                                                   u16* __restrict__ ctx, int ldqk) {
    __shared__ u16 Kl[2][64 * 128];   // [j][d], swizzle chunk ^ (row&15)
    __shared__ u16 Vl[2][128 * 64];   // [d][j], swizzle chunk ^ (row&7)
    __shared__ u16 Pl[4][16 * 64];    // per-wave P round-trip, swizzle ^ (row&7)
    int t = threadIdx.x;
    int w = t >> 6, l = t & 63;
    int lr = l & 15, q = l >> 4, lk = q * 8;
    int px = blockIdx.x, h = blockIdx.y, b = blockIdx.z;
    const float scale = 0.08838834764831845f; // 1/sqrt(128)
    int stK_gcol = (((t & 15) ^ (t >> 4)) * 8);      // K: 16 chunks per 128-u16 row
    int stV_gcol = (((t & 7) ^ ((t >> 3) & 7)) * 8); // V: 8 chunks per 64-u16 row
    const u16* Kbase = K + (size_t)b * SQ_S * ldqk + h * HD;
    const u16* Vbase = Vt + ((size_t)(b * NH + h)) * HD * SQ_S;

#pragma unroll 1
    for (int pass = 0; pass < 2; ++pass) {
        int qt = pass == 0 ? px : 31 - px;
        int q0 = qt * 64;
        int njt = qt + 1;

        // Q fragments resident in registers: wave w handles q-rows q0+w*16 .. +15
        bf16x8 qf[4];
        {
            const u16* qp = Q + ((size_t)(b * SQ_S + q0 + w * 16 + lr)) * ldqk + h * HD;
#pragma unroll
            for (int kd = 0; kd < 4; ++kd)
                qf[kd] = *(const bf16x8*)(qp + kd * 32 + lk);
        }

        f32x4 o[8] = {};
        float m_r[4], l_r[4];
#pragma unroll
        for (int r = 0; r < 4; ++r) { m_r[r] = -3.0e38f; l_r[r] = 0.f; }

        // prefetch tile 0 into buffer 0
        {
            int e = t * 8;
#pragma unroll
            for (int c = 0; c < 4; ++c) {
                int eK = c * 2048 + e;
                load_lds16(Kbase + (size_t)(eK >> 7) * ldqk + stK_gcol, Kl[0] + eK);
            }
#pragma unroll
            for (int c = 0; c < 4; ++c) {
                int eV = c * 2048 + e;
                load_lds16(Vbase + (size_t)(eV >> 6) * SQ_S + stV_gcol, Vl[0] + eV);
            }
        }

#pragma unroll 1
        for (int jt = 0; jt < njt; ++jt) {
            __syncthreads(); // drains vmcnt: buffer jt&1 staged; all waves done with other buffer
            // issue prefetch of tile jt+1 into the other buffer (overlaps compute below)
            if (jt + 1 < njt) {
                int j1 = (jt + 1) * 64;
                u16* Kd = Kl[(jt + 1) & 1];
                u16* Vd = Vl[(jt + 1) & 1];
                int e = t * 8;
#pragma unroll
                for (int c = 0; c < 4; ++c) {
                    int eK = c * 2048 + e;
                    load_lds16(Kbase + (size_t)(j1 + (eK >> 7)) * ldqk + stK_gcol, Kd + eK);
                }
#pragma unroll
                for (int c = 0; c < 4; ++c) {
                    int eV = c * 2048 + e;
                    load_lds16(Vbase + (size_t)(eV >> 6) * SQ_S + j1 + stV_gcol, Vd + eV);
                }
            }
            const u16* Kc = Kl[jt & 1];
            const u16* Vc = Vl[jt & 1];

            // S = Q K^T for this wave's 16 q-rows x 64 j-cols
            f32x4 s[4] = {};
#pragma unroll
            for (int kd = 0; kd < 4; ++kd) {
#pragma unroll
                for (int nt = 0; nt < 4; ++nt) {
                    bf16x8 kb = *(const bf16x8*)(Kc + (nt * 16 + lr) * 128 +
                                                 (((kd * 4 + q) ^ lr) * 8));
                    s[nt] = __builtin_amdgcn_mfma_f32_16x16x32_bf16(qf[kd], kb, s[nt], 0, 0, 0);
                }
            }
            float sv[4][4];
            bool diag = (jt == qt); // j0 == q0 tile needs masking
#pragma unroll
            for (int nt = 0; nt < 4; ++nt)
#pragma unroll
                for (int r = 0; r < 4; ++r) {
                    float v = s[nt][r] * scale;
                    // C layout: q_local = w*16 + q*4 + r, j_local = nt*16 + lr
                    if (diag && (nt * 16 + lr > w * 16 + q * 4 + r)) v = -3.0e38f;
                    sv[nt][r] = v;
                }
            // row max across 64 j
            float mx[4];
#pragma unroll
            for (int r = 0; r < 4; ++r)
                mx[r] = fmaxf(fmaxf(sv[0][r], sv[1][r]), fmaxf(sv[2][r], sv[3][r]));
#pragma unroll
            for (int d = 1; d < 16; d <<= 1)
#pragma unroll
                for (int r = 0; r < 4; ++r)
                    mx[r] = fmaxf(mx[r], __shfl_xor(mx[r], d, 64));
            float al[4];
#pragma unroll
            for (int r = 0; r < 4; ++r) {
                float mn = fmaxf(m_r[r], mx[r]);
                al[r] = __expf(m_r[r] - mn);
                m_r[r] = mn;
            }
            // P = exp(s - m), row sums
            float rs[4] = {0.f, 0.f, 0.f, 0.f};
            float pv[4][4];
#pragma unroll
            for (int nt = 0; nt < 4; ++nt)
#pragma unroll
                for (int r = 0; r < 4; ++r) {
                    float p = __expf(sv[nt][r] - m_r[r]);
                    pv[nt][r] = p;
                    rs[r] += p;
                }
#pragma unroll
            for (int d = 1; d < 16; d <<= 1)
#pragma unroll
                for (int r = 0; r < 4; ++r)
                    rs[r] += __shfl_xor(rs[r], d, 64);
#pragma unroll
            for (int r = 0; r < 4; ++r)
                l_r[r] = l_r[r] * al[r] + rs[r];
            // rescale O
#pragma unroll
            for (int nd = 0; nd < 8; ++nd)
#pragma unroll
                for (int r = 0; r < 4; ++r)
                    o[nd][r] *= al[r];
            // P: C-layout regs -> LDS -> A-fragment layout (per-wave, intra-wave sync)
            u16* pw = Pl[w];
#pragma unroll
            for (int nt = 0; nt < 4; ++nt)
#pragma unroll
                for (int r = 0; r < 4; ++r) {
                    int prow = q * 4 + r;
                    int pcol = nt * 16 + lr;
                    pw[prow * 64 + (((pcol >> 3) ^ (prow & 7)) * 8) + (pcol & 7)] = f2bf(pv[nt][r]);
                }
            asm volatile("s_waitcnt lgkmcnt(0)" ::: "memory");
            // O += P V
#pragma unroll
            for (int kj = 0; kj < 2; ++kj) {
                bf16x8 pa = *(const bf16x8*)(pw + lr * 64 + (((kj * 4 + q) ^ (lr & 7)) * 8));
#pragma unroll
                for (int nd = 0; nd < 8; ++nd) {
                    bf16x8 vb = *(const bf16x8*)(Vc + (nd * 16 + lr) * 64 +
                                                 (((kj * 4 + q) ^ (lr & 7)) * 8));
                    o[nd] = __builtin_amdgcn_mfma_f32_16x16x32_bf16(pa, vb, o[nd], 0, 0, 0);
                }
            }
        }
        // epilogue: ctx[b*S+q][h*HD+d] = O / l
#pragma unroll
        for (int r = 0; r < 4; ++r) l_r[r] = 1.f / l_r[r];
#pragma unroll
        for (int nd = 0; nd < 8; ++nd)
#pragma unroll
            for (int r = 0; r < 4; ++r) {
                int row = q0 + w * 16 + q * 4 + r;
                int col = h * HD + nd * 16 + lr;
                ctx[((size_t)(b * SQ_S + row)) * DIM + col] = f2bf(o[nd][r] * l_r[r]);
            }
        __syncthreads(); // all waves done reading LDS before next pass restages buffer 0
    }
}

extern "C" void kernel_launch(void* const* d_in, const int* in_sizes, int n_in,
                              void* d_out, int out_size, void* d_ws, size_t ws_size,
                              hipStream_t stream) {
    const float* x  = (const float*)d_in[0];
    const float* Wq = (const float*)d_in[1];
    const float* Wk = (const float*)d_in[2];
    const float* Wv = (const float*)d_in[3];
    const float* Wo = (const float*)d_in[4];
    const float* bo = (const float*)d_in[5];
    float* out = (float*)d_out;

    char* p = (char*)d_ws;
    const size_t SZ_ACT  = (size_t)NROWS * DIM * 2;  // 16 MB
    const size_t SZ_W    = (size_t)DIM * DIM * 2;    // 8 MB
    const size_t SZ_QKV  = (size_t)NROWS * NQKV * 2; // 48 MB
    u16* Xb   = (u16*)(p);                                  // 16 MB
    u16* Wqkv = (u16*)(p + SZ_ACT);                         // 24 MB (Wq^T,Wk^T,Wv^T contiguous)
    u16* Wot  = (u16*)(p + SZ_ACT + 3 * SZ_W);              // 8 MB
    u16* QKV  = (u16*)(p + SZ_ACT + 4 * SZ_W);              // 48 MB
    u16* Vt   = (u16*)(p + SZ_ACT + 4 * SZ_W + SZ_QKV);     // 16 MB
    u16* Cx   = (u16*)(p + 2 * SZ_ACT + 4 * SZ_W + SZ_QKV); // 16 MB  (total 128 MB)

    cast_x_kernel<<<(NROWS * DIM) / 1024, 256, 0, stream>>>(x, Xb);
    transpose_w_kernel<<<dim3(DIM / 64, DIM / 64, 4), 256, 0, stream>>>(
        Wq, Wk, Wv, Wo,
        Wqkv, Wqkv + (size_t)DIM * DIM, Wqkv + 2 * (size_t)DIM * DIM, Wot);
    // fused QKV projection: [4096 x 2048] x [6144 x 2048]^T -> [4096 x 6144]
    gemm_bt_bf16<<<dim3(NQKV / 128, NROWS / 128), 256, 0, stream>>>(Xb, Wqkv, QKV, NROWS, NQKV, DIM);
    transpose_v_kernel<<<dim3(SQ_S / 64, HD / 64, NB * NH), 256, 0, stream>>>(QKV + 2 * DIM, Vt, NQKV);
    attn_kernel<<<dim3(16, NH, NB), 256, 0, stream>>>(QKV, QKV + DIM, Vt, Cx, NQKV);
    gemm_bt_f32b<<<dim3(DIM / 128, NROWS / 128), 256, 0, stream>>>(Cx, Wot, out, bo, NROWS, DIM, DIM);
}